// Round 8
// baseline (249.414 us; speedup 1.0000x reference)
//
#include <hip/hip_runtime.h>
#include <math.h>

// RPNLayer: logits = x(32768,1024) @ W(1024,16) + b; per-anchor (8) 2-class
// log-softmax CE over valid anchors; argmax + candidate mask.
//
// R7: contiguous wave reads (channel-spread) + register W-panel + fold.
//   Evidence: R4/R5/R6 all pinned at ~70-77us main; occupancy 2x and chunk
//   rotation moved NOTHING -> throughput-saturated. Cause: lane=row makes
//   every wave-instr 64 addresses at 4KB stride with IDENTICAL low 12 bits
//   -> all 64 requests hit the same L2/HBM channel -> per-instr serialization
//   (R2's 830 GB/s ~ peak/8). Harness fills (contiguous) hit 6.8 TB/s.
//   Fix: k-split across lanes. Wave s reads k-slice [s*256,(s+1)*256) of
//   each row as ONE contiguous 1KB dwordx4 (16 lines, 4 granules); the 4
//   slices cover the full 4KB row -> all channels swept.
//   - Lane l owns fixed k = s*256+l*4..+3 -> W panel (4k x 16ch) cached in
//     64 VGPRs, loaded once. Zero W traffic in the loop.
//   - Per row: 1 load + 64 FMA + channel-halving fold (each round keeps
//     half the channels: 17 shfl instead of 96) -> lane l holds
//     logit(row, ch = l>>2). One ds_write/row (16 lanes, conflict-free).
//   - No barriers in the row loop; one __syncthreads, then in-block
//     epilogue: thread t -> (row=t>>3, anchor=t&7): slice-sum + bias, CE,
//     argmax, mask; block loss-reduce; ticketed finalize writes out[0].
//   - Grid 1024 x 256thr (4 waves); 32 rows/block; ~120 VGPR -> 4 w/SIMD.
//
// d_out (float32): [0] loss | [1..262144] predict | [262145..524288] mask
// ws: [0]=loss sum [1]=count [2]=ticket [3]=pad

#define RPB 32               // rows per block

__global__ __launch_bounds__(256, 2)
void rpn_main(const float* __restrict__ x, const float* __restrict__ W,
              const float* __restrict__ b, const int* __restrict__ lab,
              float* __restrict__ out, float* __restrict__ ws)
{
    __shared__ float red[4 * RPB * 16];      // 8192 B: [slice][row][ch]
    __shared__ float rsum[8];

    const int tid  = threadIdx.x;
    const int lane = tid & 63;
    const int s    = __builtin_amdgcn_readfirstlane(tid >> 6);  // k-slice
    const int row0 = blockIdx.x * RPB;

    // ---- one-time W panel: rows k = s*256 + lane*4 + j, all 16 ch ----
    float4 wc0[4], wc1[4], wc2[4], wc3[4];   // [q] = W[k_j][4q..4q+3]
    {
        const float* wp = W + (size_t)(s * 256 + lane * 4) * 16;
#pragma unroll
        for (int q = 0; q < 4; ++q) {
            wc0[q] = *(const float4*)(wp +  0 + q * 4);
            wc1[q] = *(const float4*)(wp + 16 + q * 4);
            wc2[q] = *(const float4*)(wp + 32 + q * 4);
            wc3[q] = *(const float4*)(wp + 48 + q * 4);
        }
    }

    const float* xp = x + (size_t)row0 * 1024 + s * 256 + lane * 4;

    // 2-deep row prefetch (explicit regs; no runtime-indexed arrays)
    float4 pfA = *(const float4*)(xp);
    float4 pfB = *(const float4*)(xp + 1024);

#pragma unroll 2
    for (int r = 0; r < RPB; ++r) {
        float4 xv = pfA;
        pfA = pfB;
        if (r + 2 < RPB) pfB = *(const float4*)(xp + (size_t)(r + 2) * 1024);

        const float xs0 = xv.x, xs1 = xv.y, xs2 = xv.z, xs3 = xv.w;
        float acc[16];
#pragma unroll
        for (int q = 0; q < 4; ++q) {
            acc[4*q+0] = xs0 * wc0[q].x;
            acc[4*q+1] = xs0 * wc0[q].y;
            acc[4*q+2] = xs0 * wc0[q].z;
            acc[4*q+3] = xs0 * wc0[q].w;
        }
#pragma unroll
        for (int q = 0; q < 4; ++q) {
            acc[4*q+0] = fmaf(xs1, wc1[q].x, acc[4*q+0]);
            acc[4*q+1] = fmaf(xs1, wc1[q].y, acc[4*q+1]);
            acc[4*q+2] = fmaf(xs1, wc1[q].z, acc[4*q+2]);
            acc[4*q+3] = fmaf(xs1, wc1[q].w, acc[4*q+3]);
        }
#pragma unroll
        for (int q = 0; q < 4; ++q) {
            acc[4*q+0] = fmaf(xs2, wc2[q].x, acc[4*q+0]);
            acc[4*q+1] = fmaf(xs2, wc2[q].y, acc[4*q+1]);
            acc[4*q+2] = fmaf(xs2, wc2[q].z, acc[4*q+2]);
            acc[4*q+3] = fmaf(xs2, wc2[q].w, acc[4*q+3]);
        }
#pragma unroll
        for (int q = 0; q < 4; ++q) {
            acc[4*q+0] = fmaf(xs3, wc3[q].x, acc[4*q+0]);
            acc[4*q+1] = fmaf(xs3, wc3[q].y, acc[4*q+1]);
            acc[4*q+2] = fmaf(xs3, wc3[q].z, acc[4*q+2]);
            acc[4*q+3] = fmaf(xs3, wc3[q].w, acc[4*q+3]);
        }

        // ---- channel-halving fold: ch bit3..0 <- lane bit5..2 ----
        const bool h5 = (lane & 32) != 0;
        float k8[8];
#pragma unroll
        for (int c = 0; c < 8; ++c) {
            float keep = h5 ? acc[c + 8] : acc[c];
            float send = h5 ? acc[c]     : acc[c + 8];
            k8[c] = keep + __shfl_xor(send, 32, 64);
        }
        const bool h4 = (lane & 16) != 0;
        float k4[4];
#pragma unroll
        for (int c = 0; c < 4; ++c) {
            float keep = h4 ? k8[c + 4] : k8[c];
            float send = h4 ? k8[c]     : k8[c + 4];
            k4[c] = keep + __shfl_xor(send, 16, 64);
        }
        const bool h3 = (lane & 8) != 0;
        float k2[2];
#pragma unroll
        for (int c = 0; c < 2; ++c) {
            float keep = h3 ? k4[c + 2] : k4[c];
            float send = h3 ? k4[c]     : k4[c + 2];
            k2[c] = keep + __shfl_xor(send, 8, 64);
        }
        const bool h2 = (lane & 4) != 0;
        float keep1 = h2 ? k2[1] : k2[0];
        float send1 = h2 ? k2[0] : k2[1];
        float k1 = keep1 + __shfl_xor(send1, 4, 64);
        k1 += __shfl_xor(k1, 2, 64);         // merge k sub-groups
        k1 += __shfl_xor(k1, 1, 64);

        if ((lane & 3) == 0)
            red[(s * RPB + r) * 16 + (lane >> 2)] = k1;
    }

    __syncthreads();

    // ---- in-block epilogue: thread t -> (row = t>>3, anchor = t&7) ----
    {
        const int row = tid >> 3;
        const int a   = tid & 7;
        const int gr  = row0 + row;

        const int i0 = row * 16 + 2 * a;
        float l0 = red[0 * RPB * 16 + i0]     + red[1 * RPB * 16 + i0]
                 + red[2 * RPB * 16 + i0]     + red[3 * RPB * 16 + i0]
                 + b[2 * a];
        float l1 = red[0 * RPB * 16 + i0 + 1] + red[1 * RPB * 16 + i0 + 1]
                 + red[2 * RPB * 16 + i0 + 1] + red[3 * RPB * 16 + i0 + 1]
                 + b[2 * a + 1];

        const int lb    = lab[(size_t)gr * 8 + a];
        const int pred  = (l1 > l0) ? 1 : 0;      // strict: tie -> class 0
        const int valid = (lb != -1);
        const float m   = fmaxf(l0, l1);
        const float lse = m + logf(expf(l0 - m) + expf(l1 - m));
        const float nll = lse - ((lb == 1) ? l1 : l0);
        float lsum = valid ? nll : 0.f;
        float lcnt = valid ? 1.f : 0.f;

        out[1 + (size_t)row0 * 8 + tid]          = (float)pred;
        out[1 + 262144 + (size_t)row0 * 8 + tid] = (pred && valid) ? 1.f : 0.f;

#pragma unroll
        for (int off = 32; off > 0; off >>= 1) {
            lsum += __shfl_down(lsum, off, 64);
            lcnt += __shfl_down(lcnt, off, 64);
        }
        if (lane == 0) {
            rsum[s * 2]     = lsum;
            rsum[s * 2 + 1] = lcnt;
        }
    }
    __syncthreads();

    if (tid == 0) {
        float S = rsum[0] + rsum[2] + rsum[4] + rsum[6];
        float C = rsum[1] + rsum[3] + rsum[5] + rsum[7];
        atomicAdd(&ws[0], S);
        atomicAdd(&ws[1], C);
        __threadfence();
        unsigned int old = atomicAdd((unsigned int*)(ws + 2), 1u);
        if (old == gridDim.x - 1) {              // last block finalizes loss
            float Sf = atomicAdd(&ws[0], 0.f);
            float Cf = atomicAdd(&ws[1], 0.f);
            out[0] = Sf / fmaxf(Cf, 1.f);
        }
    }
}

extern "C" void kernel_launch(void* const* d_in, const int* in_sizes, int n_in,
                              void* d_out, int out_size, void* d_ws, size_t ws_size,
                              hipStream_t stream)
{
    const float* x   = (const float*)d_in[0];   // (64,512,1024) f32
    const float* W   = (const float*)d_in[1];   // (1024,16) f32
    const float* b   = (const float*)d_in[2];   // (16,) f32
    const int*   lab = (const int*)d_in[3];     // (64,512,8) i32 in {-1,0,1}
    float* out = (float*)d_out;
    float* ws  = (float*)d_ws;

    hipMemsetAsync(ws, 0, 16, stream);
    rpn_main<<<dim3(1024), dim3(256), 0, stream>>>(x, W, b, lab, out, ws);
}

// Round 9
// 234.123 us; speedup vs baseline: 1.0653x; 1.0653x over previous
//
#include <hip/hip_runtime.h>
#include <math.h>

// RPNLayer: logits = x(32768,1024) @ W(1024,16) + b; per-anchor (8) 2-class
// log-softmax CE over valid anchors; argmax + candidate mask.
//
// R8: deep-pipelined async global->LDS with COUNTED vmcnt (never 0 in loop).
//   Model (fits R2/R4/R5/R6/R7): x-read is capped by per-CU outstanding
//   cache-line concurrency x L3 latency (~1.6 TB/s chip-wide), independent
//   of coalescing (R2 8-seg = R4 64-seg = R7 1-seg) and occupancy (R6 2x
//   -> nil). R5 used global_load_lds but drained vmcnt(0) every chunk
//   (burst + full stall). R8 keeps 16 DMA loads in flight continuously:
//   2 slabs/wave, issue chunk ch+2 while computing ch, wait vmcnt(8).
//   - Block 256 thr = 4 waves; wave wv owns k-slice [wv*256,(wv+1)*256)
//     of the block's 64 rows. Grid 512 = 2 blocks/CU exact.
//   - W stays wave-uniform -> scalar s_load pipe (proven R4/R5/R6).
//   - Swizzle (proven R5): linear LDS dest, source quad tq=(lane&7)^rsub,
//     read col t^(lane&7): 128B-stride row reads spread across all banks.
//   - LDS 64 KB slabs (aliased as reduction buffer) -> 2 blocks/CU.
//   - In-block epilogue + ticketed loss finalize (proven R7).
//
// d_out (float32): [0] loss | [1..262144] predict | [262145..524288] mask
// ws: [0]=loss sum [1]=count [2]=ticket [3]=pad

#define ROWS   64
#define NWAVE  4
#define KSLICE 256
#define CHUNK  32            // floats per staged chunk per row
#define NCH    8             // KSLICE/CHUNK
#define SLABF  (ROWS*CHUNK)  // 2048 floats = 8 KB per slab
#define RSTR   68            // reduction row stride: 4*16 + 4 pad

typedef __attribute__((address_space(3))) void       lds_v;
typedef const __attribute__((address_space(1))) void gbl_v;

__device__ __forceinline__ void stage16(const float* g, float* l)
{
    // 16B per lane, dest = wave-uniform base + lane*16 (linear)
    __builtin_amdgcn_global_load_lds((gbl_v*)g, (lds_v*)l, 16, 0, 0);
}

__global__ __launch_bounds__(256, 2)
void rpn_main(const float* __restrict__ x, const float* __restrict__ W,
              const float* __restrict__ b, const int* __restrict__ lab,
              float* __restrict__ out, float* __restrict__ ws)
{
    __shared__ float xs[NWAVE * 2 * SLABF];  // 16384 floats = 65536 B
    float* red = xs;                         // aliased: lifetimes disjoint

    const int tid  = threadIdx.x;
    const int lane = tid & 63;
    const int wv   = __builtin_amdgcn_readfirstlane(tid >> 6);
    const int row0 = blockIdx.x * ROWS;

    const int rsub = lane >> 3;              // staging sub-row 0..7
    const int tq   = (lane & 7) ^ rsub;      // pre-swizzled source k-quad

    float* slab0 = xs + wv * (2 * SLABF);
    float* slab1 = slab0 + SLABF;
    // staging source: row (row0 + rsub + i*8), k = wv*256 + ch*32 + tq*4
    const float* gst = x + (size_t)(row0 + rsub) * 1024 + wv * KSLICE + tq * 4;
    const float* wk  = W + (size_t)(wv * KSLICE) * 16;

    float acc[16];
#pragma unroll
    for (int c = 0; c < 16; ++c) acc[c] = 0.f;

    // prologue: fill both slabs (16 loads in flight)
#pragma unroll
    for (int i = 0; i < 8; ++i) stage16(gst + i * 8192,         slab0 + i * 256);
#pragma unroll
    for (int i = 0; i < 8; ++i) stage16(gst + CHUNK + i * 8192, slab1 + i * 256);

#define FMA16(V, WROW)                                            \
    do {                                                          \
        const float* _w = (WROW);                                 \
        _Pragma("unroll")                                         \
        for (int c = 0; c < 16; ++c)                              \
            acc[c] = fmaf((V), _w[c], acc[c]);                    \
    } while (0)

#pragma unroll 1
    for (int ch = 0; ch < NCH; ++ch) {
        float* cur = (ch & 1) ? slab1 : slab0;

        // counted wait: oldest 8 (this chunk's) done; next chunk's 8 fly on
        if (ch == NCH - 1) {
            asm volatile("s_waitcnt vmcnt(0)" ::: "memory");
        } else {
            asm volatile("s_waitcnt vmcnt(8)" ::: "memory");
        }
        __builtin_amdgcn_sched_barrier(0);

        // read this lane's 32 floats (8 swizzled b128 reads)
        float4 xq[8];
#pragma unroll
        for (int t = 0; t < 8; ++t)
            xq[t] = *(const float4*)(cur + lane * 32 + ((t ^ (lane & 7)) << 2));

        // slab free once reads complete; refill with chunk ch+2
        asm volatile("s_waitcnt lgkmcnt(0)" ::: "memory");
        __builtin_amdgcn_sched_barrier(0);
        if (ch + 2 < NCH) {
            const float* g = gst + (ch + 2) * CHUNK;
#pragma unroll
            for (int i = 0; i < 8; ++i)
                stage16(g + i * 8192, cur + i * 256);
        }

        // compute: 512 FMAs cover the in-flight loads; W via s_load
        const float* wc = wk + (size_t)(ch * CHUNK) * 16;
#pragma unroll
        for (int t = 0; t < 8; ++t) {
            FMA16(xq[t].x, wc + (t * 4 + 0) * 16);
            FMA16(xq[t].y, wc + (t * 4 + 1) * 16);
            FMA16(xq[t].z, wc + (t * 4 + 2) * 16);
            FMA16(xq[t].w, wc + (t * 4 + 3) * 16);
        }
    }
#undef FMA16

    // ---- 4-way K reduction across waves via LDS (red aliases xs) ----
    __syncthreads();
    {
        float* rp = red + lane * RSTR + wv * 16;
        *(float4*)(rp + 0)  = make_float4(acc[0],  acc[1],  acc[2],  acc[3]);
        *(float4*)(rp + 4)  = make_float4(acc[4],  acc[5],  acc[6],  acc[7]);
        *(float4*)(rp + 8)  = make_float4(acc[8],  acc[9],  acc[10], acc[11]);
        *(float4*)(rp + 12) = make_float4(acc[12], acc[13], acc[14], acc[15]);
    }
    __syncthreads();

    // ---- epilogue: one thread per row (wave 0 only) ----
    if (tid < ROWS) {
        const int row = row0 + tid;
        float L[16];
#pragma unroll
        for (int c = 0; c < 16; ++c) {
            float s = 0.f;
#pragma unroll
            for (int k = 0; k < NWAVE; ++k) s += red[tid * RSTR + k * 16 + c];
            L[c] = s + b[c];
        }

        const int* labp  = lab + (size_t)row * 8;
        float*     predp = out + 1 + (size_t)row * 8;
        float*     maskp = out + 1 + 262144 + (size_t)row * 8;

        float lsum = 0.f, lcnt = 0.f;
#pragma unroll
        for (int a = 0; a < 8; ++a) {
            float l0 = L[2 * a], l1 = L[2 * a + 1];
            int   lb = labp[a];
            int   pred  = (l1 > l0) ? 1 : 0;          // strict: tie -> class 0
            int   valid = (lb != -1);
            float m   = fmaxf(l0, l1);
            float lse = m + logf(expf(l0 - m) + expf(l1 - m));
            float nll = lse - ((lb == 1) ? l1 : l0);
            if (valid) { lsum += nll; lcnt += 1.f; }
            predp[a] = (float)pred;
            maskp[a] = (pred && valid) ? 1.f : 0.f;
        }

        // tid<64 == wave 0: full-wave shuffle reduction
#pragma unroll
        for (int off = 32; off > 0; off >>= 1) {
            lsum += __shfl_down(lsum, off, 64);
            lcnt += __shfl_down(lcnt, off, 64);
        }
        if (tid == 0) {
            atomicAdd(&ws[0], lsum);
            atomicAdd(&ws[1], lcnt);
            __threadfence();
            unsigned int old = atomicAdd((unsigned int*)(ws + 2), 1u);
            if (old == gridDim.x - 1) {          // last block finalizes loss
                float Sf = atomicAdd(&ws[0], 0.f);
                float Cf = atomicAdd(&ws[1], 0.f);
                out[0] = Sf / fmaxf(Cf, 1.f);
            }
        }
    }
}

extern "C" void kernel_launch(void* const* d_in, const int* in_sizes, int n_in,
                              void* d_out, int out_size, void* d_ws, size_t ws_size,
                              hipStream_t stream)
{
    const float* x   = (const float*)d_in[0];   // (64,512,1024) f32
    const float* W   = (const float*)d_in[1];   // (1024,16) f32
    const float* b   = (const float*)d_in[2];   // (16,) f32
    const int*   lab = (const int*)d_in[3];     // (64,512,8) i32 in {-1,0,1}
    float* out = (float*)d_out;
    float* ws  = (float*)d_ws;

    hipMemsetAsync(ws, 0, 16, stream);
    rpn_main<<<dim3(512), dim3(256), 0, stream>>>(x, W, b, lab, out, ws);
}